// Round 1
// baseline (782.807 us; speedup 1.0000x reference)
//
#include <hip/hip_runtime.h>

// SimpleUpscaleConv2d: 2x nearest upsample + 3x3 conv (pad 1) + bias, wscale.
// Factored: per output parity (a,b), a 2x2 conv on the ORIGINAL 512 grid with
// combined weights:
//   a=0: rows {i-1: ky0}, {i: ky1+ky2};  a=1: rows {i: ky0+ky1}, {i+1: ky2}
//   (same for columns with b / kx)
// FLOPs drop 9/4 vs naive: 17.2 GF -> ~109 us VALU floor; memory floor ~102 us.

#define WSCALE (1.41421356237309515f / 12.0f)  // sqrt(2)/sqrt(16*3*3)
#define LW 264  // LDS row width: col c <-> global col j0-4+c (aligned f4 staging)

__global__ __launch_bounds__(256) void prep_weights(const float* __restrict__ w,
                                                    float* __restrict__ wc) {
    int t = threadIdx.x;          // 256 threads: one (ci,co) each
    int ci = t >> 4;
    int co = t & 15;
    const float* wp = w + (co * 16 + ci) * 9;   // OIHW
    float wv[3][3];
#pragma unroll
    for (int ky = 0; ky < 3; ++ky)
#pragma unroll
        for (int kx = 0; kx < 3; ++kx)
            wv[ky][kx] = wp[ky * 3 + kx] * WSCALE;
    // column combine per parity b: cs[b][ky][c]
    float cs[2][3][2];
#pragma unroll
    for (int ky = 0; ky < 3; ++ky) {
        cs[0][ky][0] = wv[ky][0];
        cs[0][ky][1] = wv[ky][1] + wv[ky][2];
        cs[1][ky][0] = wv[ky][0] + wv[ky][1];
        cs[1][ky][1] = wv[ky][2];
    }
    float* o = wc + (ci * 16 + co) * 16;  // 16 contiguous per (ci,co)
#pragma unroll
    for (int a = 0; a < 2; ++a)
#pragma unroll
        for (int b = 0; b < 2; ++b)
#pragma unroll
            for (int r = 0; r < 2; ++r)
#pragma unroll
                for (int c = 0; c < 2; ++c) {
                    float v;
                    if (a == 0) v = (r == 0) ? cs[b][0][c] : (cs[b][1][c] + cs[b][2][c]);
                    else        v = (r == 0) ? (cs[b][0][c] + cs[b][1][c]) : cs[b][2][c];
                    o[((a * 2 + b) * 2 + r) * 2 + c] = v;
                }
}

// Block: one (n, input row i, 256-col tile). 256 threads = 4 waves.
// wave -> co group of 4 (wave-uniform => scalar weight loads).
// lane -> 4 input cols -> 8 output cols x 2 output rows x 4 co = 64 outputs... 
// acc as float2 pairs over adjacent output-col pairs sharing a weight.
__global__ __launch_bounds__(256, 3) void upconv_main(
    const float* __restrict__ x, const float* __restrict__ wc,
    const float* __restrict__ bias, float* __restrict__ out) {
    __shared__ float lds[48 * LW];  // 16 ci x 3 rows (i-1,i,i+1) x 264 cols

    const int tid = threadIdx.x;
    const int lane = tid & 63;
    const int j0 = blockIdx.x << 8;  // 0 or 256
    const int i = blockIdx.y;        // 0..511
    const int n = blockIdx.z;        // 0..7

    // ---- stage input: 48 rows x 66 float4 ----
    const float* xb = x + (size_t)n * 16 * 512 * 512;
    for (int k = tid; k < 48 * 66; k += 256) {
        int rowk = k / 66;           // = ci*3 + rr
        int q = k - rowk * 66;
        int ci = rowk / 3;
        int rr = rowk - ci * 3;
        int gr = i - 1 + rr;
        int gc = j0 - 4 + (q << 2);
        float4 v = make_float4(0.f, 0.f, 0.f, 0.f);
        if ((unsigned)gr < 512u && (unsigned)gc < 512u)  // gc%4==0 => whole f4 in/out
            v = *(const float4*)(xb + ((size_t)ci * 512 + gr) * 512 + gc);
        *(float4*)(&lds[rowk * LW + (q << 2)]) = v;
    }
    __syncthreads();

    int co_b = (tid >> 6) << 2;
    co_b = __builtin_amdgcn_readfirstlane(co_b);  // force SGPR -> s_load weights

    float2 acc[4][2][2][2];  // [co][a][b][jj-pair]
#pragma unroll
    for (int co = 0; co < 4; ++co) {
        float bv = bias[co_b + co];
#pragma unroll
        for (int a = 0; a < 2; ++a)
#pragma unroll
            for (int b = 0; b < 2; ++b)
#pragma unroll
                for (int p = 0; p < 2; ++p)
                    acc[co][a][b][p] = make_float2(bv, bv);
    }

    const float4* wg4 = (const float4*)wc;
    for (int ci = 0; ci < 16; ++ci) {
        // in[rr][k] <-> global col j-1+k, j = j0 + lane*4; lds c = lane*4+3+k
        float in[3][6];
#pragma unroll
        for (int rr = 0; rr < 3; ++rr) {
            const float* base = &lds[(ci * 3 + rr) * LW + (lane << 2)];
            float2 t0 = *(const float2*)(base + 2);   // c = lane*4+2,+3 (8B aligned)
            float4 t1 = *(const float4*)(base + 4);   // c = +4..+7 (16B aligned)
            float t2 = base[8];
            in[rr][0] = t0.y; in[rr][1] = t1.x; in[rr][2] = t1.y;
            in[rr][3] = t1.z; in[rr][4] = t1.w; in[rr][5] = t2;
        }
#pragma unroll
        for (int co = 0; co < 4; ++co) {
            const float4* wp = wg4 + ((ci * 16 + co_b + co) << 2);
#pragma unroll
            for (int a = 0; a < 2; ++a)
#pragma unroll
                for (int b = 0; b < 2; ++b) {
                    float4 w = wp[a * 2 + b];  // {r0c0, r0c1, r1c0, r1c1}
#pragma unroll
                    for (int p = 0; p < 2; ++p) {
                        int jj = p << 1;
                        float2& A = acc[co][a][b][p];
                        A.x = fmaf(w.x, in[a][jj + b],       A.x);
                        A.y = fmaf(w.x, in[a][jj + 1 + b],   A.y);
                        A.x = fmaf(w.y, in[a][jj + b + 1],   A.x);
                        A.y = fmaf(w.y, in[a][jj + b + 2],   A.y);
                        A.x = fmaf(w.z, in[a + 1][jj + b],     A.x);
                        A.y = fmaf(w.z, in[a + 1][jj + 1 + b], A.y);
                        A.x = fmaf(w.w, in[a + 1][jj + b + 1], A.x);
                        A.y = fmaf(w.w, in[a + 1][jj + b + 2], A.y);
                    }
                }
        }
    }

    // ---- epilogue: 16 coalesced float4 stores ----
    const int oc0 = (j0 << 1) + (lane << 3);
#pragma unroll
    for (int co = 0; co < 4; ++co)
#pragma unroll
        for (int a = 0; a < 2; ++a) {
            float* op = out + (((size_t)(n * 16 + co_b + co)) * 1024 + (2 * i + a)) * 1024 + oc0;
            // out col 8*lane + 2*jj + b
            float4 s0 = make_float4(acc[co][a][0][0].x, acc[co][a][1][0].x,
                                    acc[co][a][0][0].y, acc[co][a][1][0].y);
            float4 s1 = make_float4(acc[co][a][0][1].x, acc[co][a][1][1].x,
                                    acc[co][a][0][1].y, acc[co][a][1][1].y);
            *(float4*)(op) = s0;
            *(float4*)(op + 4) = s1;
        }
}

extern "C" void kernel_launch(void* const* d_in, const int* in_sizes, int n_in,
                              void* d_out, int out_size, void* d_ws, size_t ws_size,
                              hipStream_t stream) {
    const float* x = (const float*)d_in[0];       // (8,16,512,512)
    const float* w = (const float*)d_in[1];       // (16,16,3,3)
    const float* bias = (const float*)d_in[2];    // (16,)
    float* out = (float*)d_out;                   // (8,16,1024,1024)
    float* wcomb = (float*)d_ws;                  // 4096 floats = 16 KB

    prep_weights<<<1, 256, 0, stream>>>(w, wcomb);
    dim3 grid(2, 512, 8);  // (col tile, row i, n)
    upconv_main<<<grid, 256, 0, stream>>>(x, wcomb, bias, out);
}